// Round 6
// baseline (73.075 us; speedup 1.0000x reference)
//
#include <hip/hip_runtime.h>

// MNIST_QNN_Classifier: analytic collapse of the reference circuit.
//
// e[b]^2 = prod_{l=0}^{11} g_l,  g_l = cos^2(a/2) or sin^2(a/2) by bit l of b,
//          a = alpha[(2^l - 1) + (b >> (12-l))].
//          Half-angle: cos^2(a/2) = 0.5 + 0.5*cos(a); sin^2 = 0.5 - 0.5*cos(a)
//          -> per-block LDS table h[i] = 0.5*cos(alpha[i]) (4095 nodes).
// qz[b] = v0^2+v1^2-v2^2-v3^2, v = first column of the 4x4 QNN unit
//         (4 layers: RY(t0) (x) RY(t1) then CNOT(0->1), all real).
// expv = sum_b e[b]^2 * qz[b];  out[0..63] = expv.
//
// Structure (R6): ONE kernel, 64 blocks x 256 threads. Each block redundantly
// computes the FULL sum (1 wave/SIMD, thetas L2-resident -- redundancy is free)
// and writes only out[blockIdx.x]. No workspace, no finish kernel, no
// cross-block communication; removes one graph node + inter-kernel drain.
// Measured floor context: harness re-poison of 256MB ws = ~40us @85% HBM peak
// dominates dur_us; kernel-side share is the last ~3us.

#define MQ 12
#define NBLK 4096   // 2^MQ

__global__ __launch_bounds__(256) void qnn_expv_all_kernel(
    const float* __restrict__ alpha,     // (4095,)
    const float* __restrict__ thetas,    // (4096, 8)
    float* __restrict__ out)             // (64,)
{
    __shared__ float s_h[NBLK - 1];      // 0.5*cos(alpha[node]), 16380 B
    __shared__ float s_part[4];

    const int tid = threadIdx.x;

    // stage 4095 node half-angle cosines (16 precise cosf per thread)
    for (int i = tid; i < NBLK - 1; i += 256)
        s_h[i] = 0.5f * cosf(alpha[i]);
    __syncthreads();

    float acc = 0.0f;

    #pragma unroll 4
    for (int k = 0; k < 16; ++k) {
        const int b = k * 256 + tid;

        // theta loads issued first within the iteration (32B/lane, coalesced)
        const float4 th0 = *reinterpret_cast<const float4*>(thetas + (size_t)b * 8);
        const float4 th1 = *reinterpret_cast<const float4*>(thetas + (size_t)b * 8 + 4);

        // --- tree amplitude squared via half-angle LDS table ---
        float e2 = 1.0f;
        #pragma unroll
        for (int l = 0; l < MQ; ++l) {
            const int node = (1 << l) - 1 + (b >> (MQ - l));
            const float h = s_h[node];
            const int bit = (b >> (MQ - 1 - l)) & 1;
            e2 *= bit ? (0.5f - h) : (0.5f + h);
        }

        // --- first column of the 4-layer 2-qubit QNN unit ---
        const float tl[8] = {th0.x, th0.y, th0.z, th0.w, th1.x, th1.y, th1.z, th1.w};
        float v0 = 1.0f, v1 = 0.0f, v2 = 0.0f, v3 = 0.0f;
        #pragma unroll
        for (int l = 0; l < 4; ++l) {
            float s0, c0, s1, c1;
            __sincosf(tl[2 * l] * 0.5f, &s0, &c0);
            __sincosf(tl[2 * l + 1] * 0.5f, &s1, &c1);
            // rot = RY(t0) (x) RY(t1); RY = [[c,-s],[s,c]]; index = q0*2+q1
            const float a01 = c1 * v0 - s1 * v1;
            const float b01 = s1 * v0 + c1 * v1;
            const float a23 = c1 * v2 - s1 * v3;
            const float b23 = s1 * v2 + c1 * v3;
            const float w0 = c0 * a01 - s0 * a23;
            const float w1 = c0 * b01 - s0 * b23;
            const float w2 = s0 * a01 + c0 * a23;
            const float w3 = s0 * b01 + c0 * b23;
            // CNOT(q0->q1): out[2] = in[3], out[3] = in[2]
            v0 = w0; v1 = w1; v2 = w3; v3 = w2;
        }

        acc += e2 * (v0 * v0 + v1 * v1 - v2 * v2 - v3 * v3);
    }

    // --- block-total: wave shuffle reduce, 4 partials, thread 0 writes ---
    #pragma unroll
    for (int off = 32; off > 0; off >>= 1)
        acc += __shfl_down(acc, off, 64);

    if ((tid & 63) == 0) s_part[tid >> 6] = acc;
    __syncthreads();

    if (tid == 0)
        out[blockIdx.x] = s_part[0] + s_part[1] + s_part[2] + s_part[3];
}

extern "C" void kernel_launch(void* const* d_in, const int* in_sizes, int n_in,
                              void* d_out, int out_size, void* d_ws, size_t ws_size,
                              hipStream_t stream) {
    // d_in[0] = x (64,4) float32 -- unused (circuit is x-independent)
    const float* alpha  = (const float*)d_in[1];   // (4095,)
    const float* thetas = (const float*)d_in[2];   // (4096, 8)
    float* out = (float*)d_out;                    // (64,)

    qnn_expv_all_kernel<<<64, 256, 0, stream>>>(alpha, thetas, out);
}

// Round 7
// 62.097 us; speedup vs baseline: 1.1768x; 1.1768x over previous
//
#include <hip/hip_runtime.h>

// MNIST_QNN_Classifier: analytic collapse of the reference circuit.
//
// e[b]^2 = prod_{l=0}^{11} g_l,  g_l = cos^2(a/2) or sin^2(a/2) by bit l of b,
//          a = alpha[(2^l - 1) + (b >> (12-l))].
//          Half-angle: cos^2(a/2) = 0.5 + 0.5*cos(a); sin^2 = 0.5 - 0.5*cos(a).
// qz[b] = v0^2+v1^2-v2^2-v3^2, v = first column of the 4x4 QNN unit
//         (4 layers: RY(t0) (x) RY(t1) then CNOT(0->1), all real).
// expv = sum_b e[b]^2 * qz[b];  out[0..63] = expv.
//
// Structure (reverted to measured-best R5): 64 blocks x 1 wave, one item per
// thread, all-register (no LDS, no barrier); per-block partial -> ws; tiny
// finish kernel broadcasts total. Measured 61.2us vs 63.6 (1x1024) and 73.1
// (64x256 redundant). Floor context: harness re-poison of 256MB ws = ~39.5us
// @85% HBM peak + replay overhead ~= 58-60us is fixed; kernel side ~3us.

#define MQ 12
#define NBLK 4096   // 2^MQ

__global__ __launch_bounds__(64) void qnn_partial_kernel(
    const float* __restrict__ alpha,     // (4095,)
    const float* __restrict__ thetas,    // (4096, 8)
    float* __restrict__ partial)         // (64,) in ws
{
    const int b = blockIdx.x * 64 + threadIdx.x;

    // issue theta loads first; latency hides under the tree cosines
    const float4 th0 = *reinterpret_cast<const float4*>(thetas + (size_t)b * 8);
    const float4 th1 = *reinterpret_cast<const float4*>(thetas + (size_t)b * 8 + 4);

    // --- tree amplitude squared: 12 path nodes, half-angle identity ---
    float e2 = 1.0f;
    #pragma unroll
    for (int l = 0; l < MQ; ++l) {
        const int node = (1 << l) - 1 + (b >> (MQ - l));
        const float h = 0.5f * cosf(alpha[node]);
        const int bit = (b >> (MQ - 1 - l)) & 1;
        e2 *= bit ? (0.5f - h) : (0.5f + h);
    }

    // --- first column of the 4-layer 2-qubit QNN unit ---
    const float tl[8] = {th0.x, th0.y, th0.z, th0.w, th1.x, th1.y, th1.z, th1.w};
    float v0 = 1.0f, v1 = 0.0f, v2 = 0.0f, v3 = 0.0f;
    #pragma unroll
    for (int l = 0; l < 4; ++l) {
        float s0, c0, s1, c1;
        __sincosf(tl[2 * l] * 0.5f, &s0, &c0);
        __sincosf(tl[2 * l + 1] * 0.5f, &s1, &c1);
        // rot = RY(t0) (x) RY(t1); RY = [[c,-s],[s,c]]; index = q0*2+q1
        const float a01 = c1 * v0 - s1 * v1;
        const float b01 = s1 * v0 + c1 * v1;
        const float a23 = c1 * v2 - s1 * v3;
        const float b23 = s1 * v2 + c1 * v3;
        const float w0 = c0 * a01 - s0 * a23;
        const float w1 = c0 * b01 - s0 * b23;
        const float w2 = s0 * a01 + c0 * a23;
        const float w3 = s0 * b01 + c0 * b23;
        // CNOT(q0->q1): out[2] = in[3], out[3] = in[2]
        v0 = w0; v1 = w1; v2 = w3; v3 = w2;
    }
    const float qz = v0 * v0 + v1 * v1 - v2 * v2 - v3 * v3;

    // --- per-wave partial ---
    float acc = e2 * qz;
    #pragma unroll
    for (int off = 32; off > 0; off >>= 1)
        acc += __shfl_down(acc, off, 64);

    if (threadIdx.x == 0) partial[blockIdx.x] = acc;
}

__global__ __launch_bounds__(64) void qnn_finish_kernel(
    const float* __restrict__ partial,   // (64,) in ws
    float* __restrict__ out)             // (64,)
{
    float t = partial[threadIdx.x];
    #pragma unroll
    for (int off = 32; off > 0; off >>= 1)
        t += __shfl_down(t, off, 64);
    t = __shfl(t, 0, 64);                // broadcast total to all 64 lanes
    out[threadIdx.x] = t;
}

extern "C" void kernel_launch(void* const* d_in, const int* in_sizes, int n_in,
                              void* d_out, int out_size, void* d_ws, size_t ws_size,
                              hipStream_t stream) {
    // d_in[0] = x (64,4) float32 -- unused (circuit is x-independent)
    const float* alpha  = (const float*)d_in[1];   // (4095,)
    const float* thetas = (const float*)d_in[2];   // (4096, 8)
    float* out     = (float*)d_out;                // (64,)
    float* partial = (float*)d_ws;                 // 64 floats of scratch

    qnn_partial_kernel<<<64, 64, 0, stream>>>(alpha, thetas, partial);
    qnn_finish_kernel<<<1, 64, 0, stream>>>(partial, out);
}